// Round 1
// baseline (48.470 us; speedup 1.0000x reference)
//
#include <hip/hip_runtime.h>

// out[b,t,c] = (1/(t+1)) * sum_{s<=t} x[b,s,c]   — causal running mean over T.
// x: (16, 4096, 128) fp32. Two-phase chunked prefix scan along T.

constexpr int Bb = 16;
constexpr int Tt = 4096;
constexpr int Cc = 128;
constexpr int C2 = Cc / 2;   // float2 lanes: 64 lanes cover C exactly (one wave)

// K1: per-chunk column sums -> S[b*nchunk + ch][c2]  (float2)
__global__ __launch_bounds__(64) void avg_partial(const float2* __restrict__ x,
                                                  float2* __restrict__ S,
                                                  int nl, int ct) {
    int blk = blockIdx.x;
    int ch  = blk & ((1 << nl) - 1);
    int b   = blk >> nl;
    int c2  = threadIdx.x;

    const float2* xp = x + (size_t)b * (Tt * C2) + (size_t)ch * ct * C2 + c2;
    float sx = 0.f, sy = 0.f;
#pragma unroll 4
    for (int t = 0; t < ct; ++t) {
        float2 v = xp[(size_t)t * C2];
        sx += v.x; sy += v.y;
    }
    S[(size_t)blk * C2 + c2] = make_float2(sx, sy);
}

// K2: offset = sum of preceding chunk sums, then serial in-chunk scan + scale.
__global__ __launch_bounds__(64) void avg_scan(const float2* __restrict__ x,
                                               const float2* __restrict__ S,
                                               float2* __restrict__ out,
                                               int nl, int ct) {
    int blk = blockIdx.x;
    int ch  = blk & ((1 << nl) - 1);
    int b   = blk >> nl;
    int c2  = threadIdx.x;

    float ox = 0.f, oy = 0.f;
    if (nl > 0) {
        const float2* Sp = S + ((size_t)b << nl) * C2 + c2;
        for (int k = 0; k < ch; ++k) {
            float2 v = Sp[(size_t)k * C2];
            ox += v.x; oy += v.y;
        }
    }

    size_t base = (size_t)b * (Tt * C2) + (size_t)ch * ct * C2 + c2;
    const float2* xp = x + base;
    float2*       op = out + base;
    int t0 = ch * ct;
#pragma unroll 4
    for (int t = 0; t < ct; ++t) {
        float2 v = xp[(size_t)t * C2];
        ox += v.x; oy += v.y;
        float inv = 1.0f / (float)(t0 + t + 1);
        op[(size_t)t * C2] = make_float2(ox * inv, oy * inv);
    }
}

extern "C" void kernel_launch(void* const* d_in, const int* in_sizes, int n_in,
                              void* d_out, int out_size, void* d_ws, size_t ws_size,
                              hipStream_t stream) {
    const float2* x   = (const float2*)d_in[0];
    float2*       out = (float2*)d_out;
    float2*       S   = (float2*)d_ws;

    // Pick largest NCHUNK=2^nl (<=128) whose chunk-sum table fits in d_ws.
    int nl = 7;
    while (nl > 0 && ws_size < (((size_t)Bb * Cc * sizeof(float)) << nl)) --nl;
    int nchunk = 1 << nl;
    int ct     = Tt / nchunk;
    int nblk   = Bb * nchunk;

    if (nl > 0)
        avg_partial<<<nblk, 64, 0, stream>>>(x, S, nl, ct);
    avg_scan<<<nblk, 64, 0, stream>>>(x, S, out, nl, ct);
}

// Round 2
// 31.568 us; speedup vs baseline: 1.5354x; 1.5354x over previous
//
#include <hip/hip_runtime.h>

// out[b,t,c] = (1/(t+1)) * sum_{s<=t} x[b,s,c]  — causal running mean over T.
// x: (16, 4096, 128) fp32. Three-phase chunked prefix scan along T:
//   K1: per-chunk column sums        (reads x: 32 MiB HBM)
//   K1.5: exclusive scan of sums     (tiny, L2-resident)
//   K2: offset + in-chunk scan+scale (reads x from L3, writes out: 32 MiB)

constexpr int Bb = 16;
constexpr int Tt = 4096;
constexpr int Cc = 128;
constexpr int C2 = Cc / 2;   // 64 float2 lanes = one wave covers C exactly

// ---------- fast path: compile-time chunk length, fully unrolled ----------
template <int CT>
__global__ __launch_bounds__(64) void k1_sums(const float2* __restrict__ x,
                                              float2* __restrict__ S, int nl) {
    int blk = blockIdx.x;
    int ch  = blk & ((1 << nl) - 1);
    int b   = blk >> nl;
    int c2  = threadIdx.x;
    const float2* xp = x + (size_t)b * (Tt * C2) + (size_t)ch * CT * C2 + c2;

    float2 v[CT];
#pragma unroll
    for (int t = 0; t < CT; ++t) v[t] = xp[(size_t)t * C2];   // all loads in flight
    float sx = 0.f, sy = 0.f;
#pragma unroll
    for (int t = 0; t < CT; ++t) { sx += v[t].x; sy += v[t].y; }
    S[(size_t)blk * C2 + c2] = make_float2(sx, sy);
}

// exclusive scan of chunk sums per batch: E[ch] = sum_{k<ch} S[k]
__global__ __launch_bounds__(64) void k_scan_chunks(const float2* __restrict__ S,
                                                    float2* __restrict__ E,
                                                    int nchunk) {
    int b  = blockIdx.x;
    int c2 = threadIdx.x;
    const float2* Sp = S + (size_t)b * nchunk * C2 + c2;
    float2*       Ep = E + (size_t)b * nchunk * C2 + c2;
    float ox = 0.f, oy = 0.f;
#pragma unroll 8
    for (int ch = 0; ch < nchunk; ++ch) {
        Ep[(size_t)ch * C2] = make_float2(ox, oy);
        float2 v = Sp[(size_t)ch * C2];
        ox += v.x; oy += v.y;
    }
}

template <int CT>
__global__ __launch_bounds__(64) void k2_scan(const float2* __restrict__ x,
                                              const float2* __restrict__ E,
                                              float2* __restrict__ out, int nl) {
    int blk = blockIdx.x;
    int ch  = blk & ((1 << nl) - 1);
    int b   = blk >> nl;
    int c2  = threadIdx.x;

    size_t base = (size_t)b * (Tt * C2) + (size_t)ch * CT * C2 + c2;
    const float2* xp = x + base;
    float2*       op = out + base;

    float2 off = E[(size_t)blk * C2 + c2];

    float2 v[CT];
#pragma unroll
    for (int t = 0; t < CT; ++t) v[t] = xp[(size_t)t * C2];   // all loads in flight
    float ox = off.x, oy = off.y;
    int t0 = ch * CT;
#pragma unroll
    for (int t = 0; t < CT; ++t) {
        ox += v[t].x; oy += v[t].y;
        float inv = 1.0f / (float)(t0 + t + 1);
        op[(size_t)t * C2] = make_float2(ox * inv, oy * inv);
    }
}

// ---------- generic fallback (tiny ws): round-1 style, runtime ct ----------
__global__ __launch_bounds__(64) void k1g(const float2* __restrict__ x,
                                          float2* __restrict__ S, int nl, int ct) {
    int blk = blockIdx.x, ch = blk & ((1 << nl) - 1), b = blk >> nl, c2 = threadIdx.x;
    const float2* xp = x + (size_t)b * (Tt * C2) + (size_t)ch * ct * C2 + c2;
    float sx = 0.f, sy = 0.f;
#pragma unroll 8
    for (int t = 0; t < ct; ++t) { float2 v = xp[(size_t)t * C2]; sx += v.x; sy += v.y; }
    S[(size_t)blk * C2 + c2] = make_float2(sx, sy);
}

__global__ __launch_bounds__(64) void k2g(const float2* __restrict__ x,
                                          const float2* __restrict__ S,
                                          float2* __restrict__ out, int nl, int ct) {
    int blk = blockIdx.x, ch = blk & ((1 << nl) - 1), b = blk >> nl, c2 = threadIdx.x;
    float ox = 0.f, oy = 0.f;
    if (nl > 0) {
        const float2* Sp = S + ((size_t)b << nl) * C2 + c2;
#pragma unroll 8
        for (int k = 0; k < ch; ++k) { float2 v = Sp[(size_t)k * C2]; ox += v.x; oy += v.y; }
    }
    size_t base = (size_t)b * (Tt * C2) + (size_t)ch * ct * C2 + c2;
    const float2* xp = x + base;
    float2*       op = out + base;
    int t0 = ch * ct;
#pragma unroll 8
    for (int t = 0; t < ct; ++t) {
        float2 v = xp[(size_t)t * C2];
        ox += v.x; oy += v.y;
        float inv = 1.0f / (float)(t0 + t + 1);
        op[(size_t)t * C2] = make_float2(ox * inv, oy * inv);
    }
}

extern "C" void kernel_launch(void* const* d_in, const int* in_sizes, int n_in,
                              void* d_out, int out_size, void* d_ws, size_t ws_size,
                              hipStream_t stream) {
    const float2* x   = (const float2*)d_in[0];
    float2*       out = (float2*)d_out;

    // Need two tables (S and E): 2 * (Bb<<nl) * C2 * sizeof(float2) bytes.
    int nl = 8;
    while (nl > 4 && ws_size < (((size_t)2 * Bb * C2 * sizeof(float2)) << nl)) --nl;

    int nchunk = 1 << nl;
    int ct     = Tt / nchunk;
    int nblk   = Bb * nchunk;

    float2* S = (float2*)d_ws;
    float2* E = S + (size_t)nblk * C2;

    bool fast = (ws_size >= (((size_t)2 * Bb * C2 * sizeof(float2)) << nl));
    if (fast) {
        switch (ct) {
            case 16:
                k1_sums<16><<<nblk, 64, 0, stream>>>(x, S, nl);
                k_scan_chunks<<<Bb, 64, 0, stream>>>(S, E, nchunk);
                k2_scan<16><<<nblk, 64, 0, stream>>>(x, E, out, nl);
                return;
            case 32:
                k1_sums<32><<<nblk, 64, 0, stream>>>(x, S, nl);
                k_scan_chunks<<<Bb, 64, 0, stream>>>(S, E, nchunk);
                k2_scan<32><<<nblk, 64, 0, stream>>>(x, E, out, nl);
                return;
            case 64:
                k1_sums<64><<<nblk, 64, 0, stream>>>(x, S, nl);
                k_scan_chunks<<<Bb, 64, 0, stream>>>(S, E, nchunk);
                k2_scan<64><<<nblk, 64, 0, stream>>>(x, E, out, nl);
                return;
            case 128:
                k1_sums<128><<<nblk, 64, 0, stream>>>(x, S, nl);
                k_scan_chunks<<<Bb, 64, 0, stream>>>(S, E, nchunk);
                k2_scan<128><<<nblk, 64, 0, stream>>>(x, E, out, nl);
                return;
            case 256:
                k1_sums<256><<<nblk, 64, 0, stream>>>(x, S, nl);
                k_scan_chunks<<<Bb, 64, 0, stream>>>(S, E, nchunk);
                k2_scan<256><<<nblk, 64, 0, stream>>>(x, E, out, nl);
                return;
            default: break;
        }
    }
    // fallback: single-table two-kernel (needs (Bb<<nl)*C2*8 bytes; nl may be 0)
    nl = 7;
    while (nl > 0 && ws_size < (((size_t)Bb * C2 * sizeof(float2)) << nl)) --nl;
    nchunk = 1 << nl; ct = Tt / nchunk; nblk = Bb * nchunk;
    if (nl > 0) k1g<<<nblk, 64, 0, stream>>>(x, S, nl, ct);
    k2g<<<nblk, 64, 0, stream>>>(x, S, out, nl, ct);
}

// Round 3
// 26.572 us; speedup vs baseline: 1.8241x; 1.1880x over previous
//
#include <hip/hip_runtime.h>

// out[b,t,c] = (1/(t+1)) * sum_{s<=t} x[b,s,c]  — causal running mean over T.
// x: (16, 4096, 128) fp32. Two-kernel chunked prefix scan along T:
//   K1: per-chunk column sums -> S           (reads x: 32 MiB HBM)
//   K2: offset = sum of own predecessors' S (L2/L3-resident, ascending ->
//       bitwise deterministic), in-chunk scan + scale, write out.
// NCHUNK=128, CT=32: 2048 one-wave blocks per kernel (8 waves/CU).

constexpr int Bb = 16;
constexpr int Tt = 4096;
constexpr int Cc = 128;
constexpr int C2 = Cc / 2;   // 64 float2 lanes = one wave covers C exactly

template <int CT>
__global__ __launch_bounds__(64) void k1_sums(const float2* __restrict__ x,
                                              float2* __restrict__ S, int nl) {
    int blk = blockIdx.x;
    int ch  = blk & ((1 << nl) - 1);
    int b   = blk >> nl;
    int c2  = threadIdx.x;
    const float2* xp = x + (size_t)b * (Tt * C2) + (size_t)ch * CT * C2 + c2;

    float2 v[CT];
#pragma unroll
    for (int t = 0; t < CT; ++t) v[t] = xp[(size_t)t * C2];   // all loads in flight
    float sx = 0.f, sy = 0.f;
#pragma unroll
    for (int t = 0; t < CT; ++t) { sx += v[t].x; sy += v[t].y; }
    S[(size_t)blk * C2 + c2] = make_float2(sx, sy);
}

template <int CT>
__global__ __launch_bounds__(64) void k2_scan(const float2* __restrict__ x,
                                              const float2* __restrict__ S,
                                              float2* __restrict__ out, int nl) {
    int blk = blockIdx.x;
    int ch  = blk & ((1 << nl) - 1);
    int b   = blk >> nl;
    int c2  = threadIdx.x;

    size_t base = (size_t)b * (Tt * C2) + (size_t)ch * CT * C2 + c2;
    const float2* xp = x + base;
    float2*       op = out + base;

    // Issue the big x loads first so they are in flight during the offset sum.
    float2 v[CT];
#pragma unroll
    for (int t = 0; t < CT; ++t) v[t] = xp[(size_t)t * C2];

    // offset = sum of preceding chunk sums (ascending => fixed association,
    // bitwise deterministic across replays). <=127 L2-resident float2 loads.
    const float2* Sp = S + ((size_t)b << nl) * C2 + c2;
    float ox = 0.f, oy = 0.f;
#pragma unroll 8
    for (int k = 0; k < ch; ++k) {
        float2 w = Sp[(size_t)k * C2];
        ox += w.x; oy += w.y;
    }

    int t0 = ch * CT;
#pragma unroll
    for (int t = 0; t < CT; ++t) {
        ox += v[t].x; oy += v[t].y;
        float inv = 1.0f / (float)(t0 + t + 1);
        op[(size_t)t * C2] = make_float2(ox * inv, oy * inv);
    }
}

// ---------- generic fallback (tiny ws): runtime ct ----------
__global__ __launch_bounds__(64) void k1g(const float2* __restrict__ x,
                                          float2* __restrict__ S, int nl, int ct) {
    int blk = blockIdx.x, ch = blk & ((1 << nl) - 1), b = blk >> nl, c2 = threadIdx.x;
    const float2* xp = x + (size_t)b * (Tt * C2) + (size_t)ch * ct * C2 + c2;
    float sx = 0.f, sy = 0.f;
#pragma unroll 8
    for (int t = 0; t < ct; ++t) { float2 v = xp[(size_t)t * C2]; sx += v.x; sy += v.y; }
    S[(size_t)blk * C2 + c2] = make_float2(sx, sy);
}

__global__ __launch_bounds__(64) void k2g(const float2* __restrict__ x,
                                          const float2* __restrict__ S,
                                          float2* __restrict__ out, int nl, int ct) {
    int blk = blockIdx.x, ch = blk & ((1 << nl) - 1), b = blk >> nl, c2 = threadIdx.x;
    float ox = 0.f, oy = 0.f;
    if (nl > 0) {
        const float2* Sp = S + ((size_t)b << nl) * C2 + c2;
#pragma unroll 8
        for (int k = 0; k < ch; ++k) { float2 v = Sp[(size_t)k * C2]; ox += v.x; oy += v.y; }
    }
    size_t base = (size_t)b * (Tt * C2) + (size_t)ch * ct * C2 + c2;
    const float2* xp = x + base;
    float2*       op = out + base;
    int t0 = ch * ct;
#pragma unroll 8
    for (int t = 0; t < ct; ++t) {
        float2 v = xp[(size_t)t * C2];
        ox += v.x; oy += v.y;
        float inv = 1.0f / (float)(t0 + t + 1);
        op[(size_t)t * C2] = make_float2(ox * inv, oy * inv);
    }
}

extern "C" void kernel_launch(void* const* d_in, const int* in_sizes, int n_in,
                              void* d_out, int out_size, void* d_ws, size_t ws_size,
                              hipStream_t stream) {
    const float2* x   = (const float2*)d_in[0];
    float2*       out = (float2*)d_out;
    float2*       S   = (float2*)d_ws;

    // Fast path: NCHUNK=128 (nl=7), CT=32. S table = 2048*64*8 B = 1 MiB.
    constexpr int NL = 7;
    constexpr int CT = Tt / (1 << NL);          // 32
    size_t s_bytes = ((size_t)Bb << NL) * C2 * sizeof(float2);

    if (ws_size >= s_bytes) {
        int nblk = Bb << NL;
        k1_sums<CT><<<nblk, 64, 0, stream>>>(x, S, NL);
        k2_scan<CT><<<nblk, 64, 0, stream>>>(x, S, out, NL);
        return;
    }

    // Fallback: shrink chunk table until it fits (nl may reach 0).
    int nl = 7;
    while (nl > 0 && ws_size < (((size_t)Bb * C2 * sizeof(float2)) << nl)) --nl;
    int nchunk = 1 << nl, ct = Tt / nchunk, nblk = Bb * nchunk;
    if (nl > 0) k1g<<<nblk, 64, 0, stream>>>(x, S, nl, ct);
    k2g<<<nblk, 64, 0, stream>>>(x, S, out, nl, ct);
}